// Round 1
// baseline (566.806 us; speedup 1.0000x reference)
//
#include <hip/hip_runtime.h>

typedef __attribute__((ext_vector_type(4))) float f32x4;
typedef __attribute__((ext_vector_type(8))) short short8;
typedef __attribute__((ext_vector_type(4))) unsigned short us4;
typedef unsigned short u16;

__device__ __forceinline__ u16 f2b(float f) {
  union { float f; unsigned u; } a; a.f = f;
  unsigned r = a.u + 0x7fffu + ((a.u >> 16) & 1u);
  return (u16)(r >> 16);
}
__device__ __forceinline__ float b2f(u16 u) {
  union { unsigned u; float f; } a; a.u = ((unsigned)u) << 16;
  return a.f;
}
// XOR swizzle for [rows][128B] LDS tiles (G4 fix for 16-way conflicts)
#define SWZ(r, byteoff) ((((r) * 128) + (byteoff)) ^ (((r) & 7) << 4))

// ---------------- weight transpose + bf16 convert: Wt[n][k] = W[k][n] ----------------
__global__ __launch_bounds__(256) void wtrans_kernel(
    const float* w0, const float* w1, const float* w2, const float* w3,
    const float* w4, const float* w5, const float* w6, u16* wt)
{
  const float* Ws[7] = {w0, w1, w2, w3, w4, w5, w6};
  const float* W = Ws[blockIdx.z];
  u16* out = wt + (size_t)blockIdx.z * 768 * 768;
  __shared__ float tile[64][65];
  const int t = threadIdx.x;
  const int r0 = blockIdx.y * 64, c0 = blockIdx.x * 64;
#pragma unroll
  for (int i = 0; i < 4; ++i) {
    int idx = i * 256 + t;
    int r = idx >> 4, c = (idx & 15) * 4;
    f32x4 v = *(const f32x4*)(W + (size_t)(r0 + r) * 768 + (c0 + c));
    tile[r][c + 0] = v[0]; tile[r][c + 1] = v[1];
    tile[r][c + 2] = v[2]; tile[r][c + 3] = v[3];
  }
  __syncthreads();
#pragma unroll
  for (int i = 0; i < 4; ++i) {
    int idx = i * 256 + t;
    int rn = idx >> 4, c = (idx & 15) * 4;
    us4 o;
    o[0] = f2b(tile[c + 0][rn]); o[1] = f2b(tile[c + 1][rn]);
    o[2] = f2b(tile[c + 2][rn]); o[3] = f2b(tile[c + 3][rn]);
    *(us4*)(out + (size_t)(c0 + rn) * 768 + (r0 + c)) = o;
  }
}

// ---------------- QKV projection: X[M][768] f32 @ Wt^T + bias -> bf16 ----------------
// z=0,1: out [b][h][s][64]  (q, k) ; z=2: out [b][h][64][s]  (v transposed)
__global__ __launch_bounds__(256) void proj_kernel(
    const float* __restrict__ X,
    const u16* __restrict__ Wta, const u16* __restrict__ Wtb, const u16* __restrict__ Wtc,
    const float* __restrict__ ba, const float* __restrict__ bb, const float* __restrict__ bc,
    u16* __restrict__ oa, u16* __restrict__ ob, u16* __restrict__ oc,
    int S, int logS)
{
  const int z = blockIdx.z;
  const u16* Wt = (z == 0) ? Wta : (z == 1) ? Wtb : Wtc;
  const float* bias = (z == 0) ? ba : (z == 1) ? bb : bc;
  u16* out = (z == 0) ? oa : (z == 1) ? ob : oc;
  const bool vmode = (z == 2);
  const int m0 = blockIdx.x * 128, n0 = blockIdx.y * 128;
  __shared__ unsigned char sm[36864];
  unsigned char* Asm = sm;
  unsigned char* Bsm = sm + 16384;
  const int t = threadIdx.x, w = t >> 6, l = t & 63;
  const int wm = (w & 1) * 64, wn = (w >> 1) * 64;
  f32x4 acc[4][4] = {};
  for (int k0 = 0; k0 < 768; k0 += 64) {
#pragma unroll
    for (int i = 0; i < 8; ++i) {               // stage A: 128x64 f32->bf16
      int idx = i * 256 + t;
      int r = idx >> 4, c = (idx & 15) * 4;
      f32x4 v = *(const f32x4*)(X + (size_t)(m0 + r) * 768 + (k0 + c));
      us4 o; o[0] = f2b(v[0]); o[1] = f2b(v[1]); o[2] = f2b(v[2]); o[3] = f2b(v[3]);
      *(us4*)(Asm + SWZ(r, c * 2)) = o;
    }
#pragma unroll
    for (int i = 0; i < 4; ++i) {               // stage B: Wt rows n, cols k
      int idx = i * 256 + t;
      int r = idx >> 3, c8 = (idx & 7) * 8;
      short8 v = *(const short8*)(Wt + (size_t)(n0 + r) * 768 + (k0 + c8));
      *(short8*)(Bsm + SWZ(r, c8 * 2)) = v;
    }
    __syncthreads();
#pragma unroll
    for (int kc = 0; kc < 2; ++kc) {
      short8 af[4], bfr[4];
      const int koff = (kc * 32 + (l >> 4) * 8) * 2;
#pragma unroll
      for (int ms = 0; ms < 4; ++ms) {
        int row = wm + ms * 16 + (l & 15);
        af[ms] = *(const short8*)(Asm + SWZ(row, koff));
      }
#pragma unroll
      for (int ns = 0; ns < 4; ++ns) {
        int row = wn + ns * 16 + (l & 15);
        bfr[ns] = *(const short8*)(Bsm + SWZ(row, koff));
      }
#pragma unroll
      for (int ms = 0; ms < 4; ++ms)
#pragma unroll
        for (int ns = 0; ns < 4; ++ns)
          acc[ms][ns] = __builtin_amdgcn_mfma_f32_16x16x32_bf16(af[ms], bfr[ns], acc[ms][ns], 0, 0, 0);
    }
    __syncthreads();
  }
  // epilogue: bias, bounce via LDS (stride 272B), coalesced write
  float bv[4];
#pragma unroll
  for (int ns = 0; ns < 4; ++ns) bv[ns] = bias[n0 + wn + ns * 16 + (l & 15)];
#pragma unroll
  for (int ms = 0; ms < 4; ++ms)
#pragma unroll
    for (int ns = 0; ns < 4; ++ns)
#pragma unroll
      for (int i = 0; i < 4; ++i) {
        u16 u = f2b(acc[ms][ns][i] + bv[ns]);
        int mm = wm + ms * 16 + (l >> 4) * 4 + i;
        int nn = wn + ns * 16 + (l & 15);
        int row = vmode ? nn : mm, col = vmode ? mm : nn;
        *(u16*)(sm + row * 272 + col * 2) = u;
      }
  __syncthreads();
  if (!vmode) {
#pragma unroll
    for (int i = 0; i < 8; ++i) {
      int idx = i * 256 + t;
      int r = idx >> 4, c = (idx & 15) * 8;
      short8 v = *(const short8*)(sm + r * 272 + c * 2);
      int sg = m0 + r, b = sg >> logS, s = sg & (S - 1);
      int n = n0 + c, hh = n >> 6, d = n & 63;
      *(short8*)(out + (((size_t)b * 12 + hh) * S + s) * 64 + d) = v;
    }
  } else {
#pragma unroll
    for (int i = 0; i < 8; ++i) {
      int idx = i * 256 + t;
      int r = idx >> 4, c = (idx & 15) * 8;  // r: n index, c: m chunk
      short8 v = *(const short8*)(sm + r * 272 + c * 2);
      int n = n0 + r, hh = n >> 6, d = n & 63;
      int sg = m0 + c, b = sg >> logS, s = sg & (S - 1);
      *(short8*)(out + (((size_t)b * 12 + hh) * 64 + d) * S + s) = v;
    }
  }
}

// ---------------- attention: two-pass exact softmax, optional probs output ----------------
// grid (Sq/64, 12, B), block 256. Q/K: [b][h][S][64] bf16, VT: [b][h][64][Sk] bf16.
// CTX out: [b][s][h*64+d] bf16 merged. PROBS (may be null): [b][h][Sq][Sk] f32.
__global__ __launch_bounds__(256) void attn_kernel(
    const u16* __restrict__ Q, const u16* __restrict__ K, const u16* __restrict__ VT,
    u16* __restrict__ CTX, float* __restrict__ PROBS, int Sq, int Sk)
{
  const int h = blockIdx.y, b = blockIdx.z;
  const int q0 = blockIdx.x * 64;
  const int t = threadIdx.x, w = t >> 6, l = t & 63;
  const size_t bh = (size_t)b * 12 + h;
  const u16* Qp = Q + bh * Sq * 64;
  const u16* Kp = K + bh * Sk * 64;
  const u16* Vp = VT + bh * 64 * Sk;
  __shared__ unsigned char smem[24576];
  unsigned char* Ksm = smem;
  unsigned char* Vsm = smem + 8192;
  unsigned char* Psm = smem + 16384 + w * 2048;

  short8 qf[2];
  {
    int row = q0 + w * 16 + (l & 15);
    qf[0] = *(const short8*)(Qp + (size_t)row * 64 + (l >> 4) * 8);
    qf[1] = *(const short8*)(Qp + (size_t)row * 64 + 32 + (l >> 4) * 8);
  }
  float m[4], ll[4];
#pragma unroll
  for (int i = 0; i < 4; ++i) { m[i] = -1e30f; ll[i] = 0.f; }
  const int nkt = Sk >> 6;

  // ---- pass 1: row max + sum ----
  for (int kt = 0; kt < nkt; ++kt) {
#pragma unroll
    for (int i = 0; i < 2; ++i) {
      int idx = i * 256 + t;
      int r = idx >> 3, off = (idx & 7) * 16;
      short8 v = *(const short8*)(Kp + (size_t)(kt * 64 + r) * 64 + off / 2);
      *(short8*)(Ksm + SWZ(r, off)) = v;
    }
    __syncthreads();
    f32x4 sfr[4] = {};
#pragma unroll
    for (int kc = 0; kc < 2; ++kc)
#pragma unroll
      for (int sub = 0; sub < 4; ++sub) {
        int row = sub * 16 + (l & 15);
        short8 kf = *(const short8*)(Ksm + SWZ(row, (kc * 32 + (l >> 4) * 8) * 2));
        sfr[sub] = __builtin_amdgcn_mfma_f32_16x16x32_bf16(qf[kc], kf, sfr[sub], 0, 0, 0);
      }
    __syncthreads();
    float tm[4], ts[4];
#pragma unroll
    for (int i = 0; i < 4; ++i) {
      float v = fmaxf(fmaxf(sfr[0][i], sfr[1][i]), fmaxf(sfr[2][i], sfr[3][i]));
      tm[i] = v * 0.125f;
    }
#pragma unroll
    for (int d = 1; d < 16; d <<= 1)
#pragma unroll
      for (int i = 0; i < 4; ++i) tm[i] = fmaxf(tm[i], __shfl_xor(tm[i], d));
#pragma unroll
    for (int i = 0; i < 4; ++i) {
      float mn = fmaxf(m[i], tm[i]);
      ts[i] = __expf(sfr[0][i] * 0.125f - mn) + __expf(sfr[1][i] * 0.125f - mn)
            + __expf(sfr[2][i] * 0.125f - mn) + __expf(sfr[3][i] * 0.125f - mn);
      ll[i] *= __expf(m[i] - mn);
      m[i] = mn;
    }
#pragma unroll
    for (int d = 1; d < 16; d <<= 1)
#pragma unroll
      for (int i = 0; i < 4; ++i) ts[i] += __shfl_xor(ts[i], d);
#pragma unroll
    for (int i = 0; i < 4; ++i) ll[i] += ts[i];
  }
  float rl[4];
#pragma unroll
  for (int i = 0; i < 4; ++i) rl[i] = 1.0f / ll[i];

  // ---- pass 2: recompute S (bit-identical), write probs, PV ----
  f32x4 of[4] = {};
  for (int kt = 0; kt < nkt; ++kt) {
#pragma unroll
    for (int i = 0; i < 2; ++i) {
      int idx = i * 256 + t;
      int r = idx >> 3, off = (idx & 7) * 16;
      short8 v = *(const short8*)(Kp + (size_t)(kt * 64 + r) * 64 + off / 2);
      *(short8*)(Ksm + SWZ(r, off)) = v;
      short8 v2 = *(const short8*)(Vp + (size_t)r * Sk + kt * 64 + off / 2);
      *(short8*)(Vsm + SWZ(r, off)) = v2;
    }
    __syncthreads();
    f32x4 sfr[4] = {};
#pragma unroll
    for (int kc = 0; kc < 2; ++kc)
#pragma unroll
      for (int sub = 0; sub < 4; ++sub) {
        int row = sub * 16 + (l & 15);
        short8 kf = *(const short8*)(Ksm + SWZ(row, (kc * 32 + (l >> 4) * 8) * 2));
        sfr[sub] = __builtin_amdgcn_mfma_f32_16x16x32_bf16(qf[kc], kf, sfr[sub], 0, 0, 0);
      }
#pragma unroll
    for (int sub = 0; sub < 4; ++sub)
#pragma unroll
      for (int i = 0; i < 4; ++i) {
        float p = __expf(sfr[sub][i] * 0.125f - m[i]) * rl[i];
        int prow = (l >> 4) * 4 + i;
        int pcol = sub * 16 + (l & 15);
        if (PROBS)
          PROBS[(bh * Sq + q0 + w * 16 + prow) * (size_t)Sk + kt * 64 + pcol] = p;
        *(u16*)(Psm + SWZ(prow, pcol * 2)) = f2b(p);
      }
    short8 pa[2];
    {
      int row = l & 15;
      pa[0] = *(const short8*)(Psm + SWZ(row, ((l >> 4) * 8) * 2));
      pa[1] = *(const short8*)(Psm + SWZ(row, (32 + (l >> 4) * 8) * 2));
    }
#pragma unroll
    for (int kc = 0; kc < 2; ++kc)
#pragma unroll
      for (int ds = 0; ds < 4; ++ds) {
        int row = ds * 16 + (l & 15);
        short8 vb = *(const short8*)(Vsm + SWZ(row, (kc * 32 + (l >> 4) * 8) * 2));
        of[ds] = __builtin_amdgcn_mfma_f32_16x16x32_bf16(pa[kc], vb, of[ds], 0, 0, 0);
      }
    __syncthreads();
  }
  // write ctx via per-wave LDS bounce (coalesced)
#pragma unroll
  for (int ds = 0; ds < 4; ++ds)
#pragma unroll
    for (int i = 0; i < 4; ++i) {
      int prow = (l >> 4) * 4 + i, pcol = ds * 16 + (l & 15);
      *(u16*)(Psm + SWZ(prow, pcol * 2)) = f2b(of[ds][i]);
    }
#pragma unroll
  for (int i = 0; i < 2; ++i) {
    int idx = i * 64 + l;
    int r = idx >> 3, off = (idx & 7) * 16;
    short8 v = *(const short8*)(Psm + SWZ(r, off));
    int s = q0 + w * 16 + r;
    *(short8*)(CTX + ((size_t)b * Sq + s) * 768 + h * 64 + off / 2) = v;
  }
}

// ---------------- output projection: 0.5*(CA+CB) @ Wo^T + bo -> f32 ----------------
__global__ __launch_bounds__(256) void outproj_kernel(
    const u16* __restrict__ CA, const u16* __restrict__ CB,
    const u16* __restrict__ Wt, const float* __restrict__ bias,
    float* __restrict__ OUT)
{
  const int m0 = blockIdx.x * 128, n0 = blockIdx.y * 128;
  __shared__ unsigned char sm[32768];
  unsigned char* Asm = sm;
  unsigned char* Bsm = sm + 16384;
  const int t = threadIdx.x, w = t >> 6, l = t & 63;
  const int wm = (w & 1) * 64, wn = (w >> 1) * 64;
  f32x4 acc[4][4] = {};
  for (int k0 = 0; k0 < 768; k0 += 64) {
#pragma unroll
    for (int i = 0; i < 4; ++i) {
      int idx = i * 256 + t;
      int r = idx >> 3, c8 = (idx & 7) * 8;
      short8 va = *(const short8*)(CA + (size_t)(m0 + r) * 768 + (k0 + c8));
      short8 vb = *(const short8*)(CB + (size_t)(m0 + r) * 768 + (k0 + c8));
      short8 o;
#pragma unroll
      for (int j = 0; j < 8; ++j)
        o[j] = (short)f2b((b2f((u16)va[j]) + b2f((u16)vb[j])) * 0.5f);
      *(short8*)(Asm + SWZ(r, c8 * 2)) = o;
    }
#pragma unroll
    for (int i = 0; i < 4; ++i) {
      int idx = i * 256 + t;
      int r = idx >> 3, c8 = (idx & 7) * 8;
      short8 v = *(const short8*)(Wt + (size_t)(n0 + r) * 768 + (k0 + c8));
      *(short8*)(Bsm + SWZ(r, c8 * 2)) = v;
    }
    __syncthreads();
#pragma unroll
    for (int kc = 0; kc < 2; ++kc) {
      short8 af[4], bfr[4];
      const int koff = (kc * 32 + (l >> 4) * 8) * 2;
#pragma unroll
      for (int ms = 0; ms < 4; ++ms) {
        int row = wm + ms * 16 + (l & 15);
        af[ms] = *(const short8*)(Asm + SWZ(row, koff));
      }
#pragma unroll
      for (int ns = 0; ns < 4; ++ns) {
        int row = wn + ns * 16 + (l & 15);
        bfr[ns] = *(const short8*)(Bsm + SWZ(row, koff));
      }
#pragma unroll
      for (int ms = 0; ms < 4; ++ms)
#pragma unroll
        for (int ns = 0; ns < 4; ++ns)
          acc[ms][ns] = __builtin_amdgcn_mfma_f32_16x16x32_bf16(af[ms], bfr[ns], acc[ms][ns], 0, 0, 0);
    }
    __syncthreads();
  }
#pragma unroll
  for (int ms = 0; ms < 4; ++ms)
#pragma unroll
    for (int ns = 0; ns < 4; ++ns) {
      float bv = bias[n0 + wn + ns * 16 + (l & 15)];
#pragma unroll
      for (int i = 0; i < 4; ++i) {
        int mm = m0 + wm + ms * 16 + (l >> 4) * 4 + i;
        int nn = n0 + wn + ns * 16 + (l & 15);
        OUT[(size_t)mm * 768 + nn] = acc[ms][ns][i] + bv;
      }
    }
}

extern "C" void kernel_launch(void* const* d_in, const int* in_sizes, int n_in,
                              void* d_out, int out_size, void* d_ws, size_t ws_size,
                              hipStream_t stream)
{
  const float* hidden = (const float*)d_in[0];
  const float* text   = (const float*)d_in[1];
  const float* Wq  = (const float*)d_in[2];  const float* bq  = (const float*)d_in[3];
  const float* Wk  = (const float*)d_in[4];  const float* bk  = (const float*)d_in[5];
  const float* Wv  = (const float*)d_in[6];  const float* bv  = (const float*)d_in[7];
  const float* Wqt = (const float*)d_in[8];  const float* bqt = (const float*)d_in[9];
  const float* Wkt = (const float*)d_in[10]; const float* bkt = (const float*)d_in[11];
  const float* Wvt = (const float*)d_in[12]; const float* bvt = (const float*)d_in[13];
  const float* Wo  = (const float*)d_in[14]; const float* bo  = (const float*)d_in[15];

  // workspace layout (bf16 elems), total ~103 MB
  u16* wt  = (u16*)d_ws;                    // 7 * 589824
  u16* qi  = wt + 7 * 589824;               // [8][12][1024][64]
  u16* ki  = qi + 6291456;
  u16* vti = ki + 6291456;                  // [8][12][64][1024]
  u16* qt  = vti + 6291456;                 // [8][12][512][64]
  u16* ktx = qt + 3145728;
  u16* vtt = ktx + 3145728;                 // [8][12][64][512]
  u16* cii = vtt + 3145728;                 // [8][1024][768]
  u16* cit = cii + 6291456;
  u16* ctt = cit + 6291456;                 // [8][512][768]
  u16* cti = ctt + 3145728;

  float* out_img  = (float*)d_out;
  float* out_text = out_img + 6291456;
  float* weights  = out_text + 3145728;

  wtrans_kernel<<<dim3(12, 12, 7), 256, 0, stream>>>(Wq, Wk, Wv, Wqt, Wkt, Wvt, Wo, wt);

  u16* wtq  = wt;              u16* wtk  = wt + 589824;     u16* wtv  = wt + 2 * 589824;
  u16* wtqt = wt + 3 * 589824; u16* wtkt = wt + 4 * 589824; u16* wtvt = wt + 5 * 589824;
  u16* wto  = wt + 6 * 589824;

  proj_kernel<<<dim3(64, 6, 3), 256, 0, stream>>>(hidden, wtq, wtk, wtv, bq, bk, bv, qi, ki, vti, 1024, 10);
  proj_kernel<<<dim3(32, 6, 3), 256, 0, stream>>>(text, wtqt, wtkt, wtvt, bqt, bkt, bvt, qt, ktx, vtt, 512, 9);

  attn_kernel<<<dim3(16, 12, 8), 256, 0, stream>>>(qi, ki, vti, cii, weights, 1024, 1024);
  attn_kernel<<<dim3(16, 12, 8), 256, 0, stream>>>(qi, ktx, vtt, cit, nullptr, 1024, 512);
  attn_kernel<<<dim3(8, 12, 8), 256, 0, stream>>>(qt, ki, vti, cti, nullptr, 512, 1024);
  attn_kernel<<<dim3(8, 12, 8), 256, 0, stream>>>(qt, ktx, vtt, ctt, nullptr, 512, 512);

  outproj_kernel<<<dim3(64, 6), 256, 0, stream>>>(cii, cit, wto, bo, out_img);
  outproj_kernel<<<dim3(32, 6), 256, 0, stream>>>(ctt, cti, wto, bo, out_text);
}

// Round 2
// 363.410 us; speedup vs baseline: 1.5597x; 1.5597x over previous
//
#include <hip/hip_runtime.h>

typedef __attribute__((ext_vector_type(4))) float f32x4;
typedef __attribute__((ext_vector_type(8))) short short8;
typedef __attribute__((ext_vector_type(4))) unsigned short us4;
typedef unsigned short u16;

__device__ __forceinline__ u16 f2b(float f) {
  union { float f; unsigned u; } a; a.f = f;
  unsigned r = a.u + 0x7fffu + ((a.u >> 16) & 1u);
  return (u16)(r >> 16);
}
// XOR swizzle for [rows][128B] LDS tiles
#define SWZ(r, byteoff) ((((r) * 128) + (byteoff)) ^ (((r) & 7) << 4))

typedef __attribute__((address_space(1))) const void* gp1;
typedef __attribute__((address_space(3))) void* lp3;
__device__ __forceinline__ void gload16(const void* g, void* lds_wave_uniform_base) {
  __builtin_amdgcn_global_load_lds((gp1)g, (lp3)lds_wave_uniform_base, 16, 0, 0);
}

// ---------------- weight transpose + bf16 convert: Wt[n][k] = W[k][n] ----------------
__global__ __launch_bounds__(256) void wtrans_kernel(
    const float* w0, const float* w1, const float* w2, const float* w3,
    const float* w4, const float* w5, const float* w6, u16* wt)
{
  const float* Ws[7] = {w0, w1, w2, w3, w4, w5, w6};
  const float* W = Ws[blockIdx.z];
  u16* out = wt + (size_t)blockIdx.z * 768 * 768;
  __shared__ float tile[64][65];
  const int t = threadIdx.x;
  const int r0 = blockIdx.y * 64, c0 = blockIdx.x * 64;
#pragma unroll
  for (int i = 0; i < 4; ++i) {
    int idx = i * 256 + t;
    int r = idx >> 4, c = (idx & 15) * 4;
    f32x4 v = *(const f32x4*)(W + (size_t)(r0 + r) * 768 + (c0 + c));
    tile[r][c + 0] = v[0]; tile[r][c + 1] = v[1];
    tile[r][c + 2] = v[2]; tile[r][c + 3] = v[3];
  }
  __syncthreads();
#pragma unroll
  for (int i = 0; i < 4; ++i) {
    int idx = i * 256 + t;
    int rn = idx >> 4, c = (idx & 15) * 4;
    us4 o;
    o[0] = f2b(tile[c + 0][rn]); o[1] = f2b(tile[c + 1][rn]);
    o[2] = f2b(tile[c + 2][rn]); o[3] = f2b(tile[c + 3][rn]);
    *(us4*)(out + (size_t)(c0 + rn) * 768 + (r0 + c)) = o;
  }
}

// ---------------- X f32 -> bf16 convert (hidden then text, concatenated) ----------------
__global__ __launch_bounds__(256) void xconv_kernel(
    const float* __restrict__ h, const float* __restrict__ tx, u16* __restrict__ o)
{
  size_t e = ((size_t)blockIdx.x * 256 + threadIdx.x) * 8;
  const float* src; size_t off;
  if (e < 6291456) { src = h; off = e; } else { src = tx; off = e - 6291456; }
  f32x4 v0 = *(const f32x4*)(src + off), v1 = *(const f32x4*)(src + off + 4);
  short8 r;
  r[0] = (short)f2b(v0[0]); r[1] = (short)f2b(v0[1]); r[2] = (short)f2b(v0[2]); r[3] = (short)f2b(v0[3]);
  r[4] = (short)f2b(v1[0]); r[5] = (short)f2b(v1[1]); r[6] = (short)f2b(v1[2]); r[7] = (short)f2b(v1[3]);
  *(short8*)(o + e) = r;
}

// ---------------- QKV projection: Xb[M][768] bf16 @ Wt3^T + bias -> bf16 ----------------
// grid (M/128, 18). y/6 = 0,1,2 -> q [b][h][s][64], k [b][h][s][64], v [b][h][64][s]
__global__ __launch_bounds__(256) void proj_kernel(
    const u16* __restrict__ Xb, const u16* __restrict__ Wt3,
    const float* __restrict__ ba, const float* __restrict__ bb, const float* __restrict__ bc,
    u16* __restrict__ oa, u16* __restrict__ ob, u16* __restrict__ oc,
    int S, int logS)
{
  const int m0 = blockIdx.x * 128;
  const int y = blockIdx.y;
  const int z = y / 6;
  const int n0 = (y % 6) * 128;          // column within this 768-wide output
  const u16* Wt = Wt3 + (size_t)y * 128 * 768;
  const float* bias = (z == 0) ? ba : (z == 1) ? bb : bc;
  u16* out = (z == 0) ? oa : (z == 1) ? ob : oc;
  const bool vmode = (z == 2);
  __shared__ unsigned char sm[36864];
  unsigned char* Asm = sm;
  unsigned char* Bsm = sm + 16384;
  const int t = threadIdx.x, w = t >> 6, l = t & 63;
  const int wm = (w & 1) * 64, wn = (w >> 1) * 64;
  f32x4 acc[4][4] = {};
  for (int k0 = 0; k0 < 768; k0 += 64) {
#pragma unroll
    for (int j = 0; j < 4; ++j) {        // A: 128 rows x 128B, 16 chunks of 1KB
      int chunk = j * 4 + w;
      int r = chunk * 8 + (l >> 3);
      int cb = ((l & 7) * 16) ^ ((r & 7) << 4);
      gload16(Xb + (size_t)(m0 + r) * 768 + k0 + cb / 2, Asm + chunk * 1024);
    }
#pragma unroll
    for (int j = 0; j < 4; ++j) {        // B: Wt rows
      int chunk = j * 4 + w;
      int r = chunk * 8 + (l >> 3);
      int cb = ((l & 7) * 16) ^ ((r & 7) << 4);
      gload16(Wt + (size_t)r * 768 + k0 + cb / 2, Bsm + chunk * 1024);
    }
    __syncthreads();
#pragma unroll
    for (int kc = 0; kc < 2; ++kc) {
      short8 af[4], bfr[4];
      const int koff = (kc * 32 + (l >> 4) * 8) * 2;
#pragma unroll
      for (int ms = 0; ms < 4; ++ms) {
        int row = wm + ms * 16 + (l & 15);
        af[ms] = *(const short8*)(Asm + SWZ(row, koff));
      }
#pragma unroll
      for (int ns = 0; ns < 4; ++ns) {
        int row = wn + ns * 16 + (l & 15);
        bfr[ns] = *(const short8*)(Bsm + SWZ(row, koff));
      }
#pragma unroll
      for (int ms = 0; ms < 4; ++ms)
#pragma unroll
        for (int ns = 0; ns < 4; ++ns)
          acc[ms][ns] = __builtin_amdgcn_mfma_f32_16x16x32_bf16(af[ms], bfr[ns], acc[ms][ns], 0, 0, 0);
    }
    __syncthreads();
  }
  float bv[4];
#pragma unroll
  for (int ns = 0; ns < 4; ++ns) bv[ns] = bias[n0 + wn + ns * 16 + (l & 15)];
#pragma unroll
  for (int ms = 0; ms < 4; ++ms)
#pragma unroll
    for (int ns = 0; ns < 4; ++ns)
#pragma unroll
      for (int i = 0; i < 4; ++i) {
        u16 u = f2b(acc[ms][ns][i] + bv[ns]);
        int mm = wm + ms * 16 + (l >> 4) * 4 + i;
        int nn = wn + ns * 16 + (l & 15);
        int row = vmode ? nn : mm, col = vmode ? mm : nn;
        *(u16*)(sm + row * 272 + col * 2) = u;
      }
  __syncthreads();
  if (!vmode) {
#pragma unroll
    for (int i = 0; i < 8; ++i) {
      int idx = i * 256 + t;
      int r = idx >> 4, c = (idx & 15) * 8;
      short8 v = *(const short8*)(sm + r * 272 + c * 2);
      int sg = m0 + r, b = sg >> logS, s = sg & (S - 1);
      int n = n0 + c, hh = n >> 6, d = n & 63;
      *(short8*)(out + (((size_t)b * 12 + hh) * S + s) * 64 + d) = v;
    }
  } else {
#pragma unroll
    for (int i = 0; i < 8; ++i) {
      int idx = i * 256 + t;
      int r = idx >> 4, c = (idx & 15) * 8;
      short8 v = *(const short8*)(sm + r * 272 + c * 2);
      int n = n0 + r, hh = n >> 6, d = n & 63;
      int sg = m0 + c, b = sg >> logS, s = sg & (S - 1);
      *(short8*)(out + (((size_t)b * 12 + hh) * 64 + d) * S + s) = v;
    }
  }
}

// ---------------- fused dual-source attention ----------------
__device__ __forceinline__ void stage_k(const u16* Kp, int kt, unsigned char* Ksm, int w, int l) {
#pragma unroll
  for (int j = 0; j < 2; ++j) {
    int chunk = j * 4 + w;
    int r = chunk * 8 + (l >> 3);
    int cb = ((l & 7) * 16) ^ ((r & 7) << 4);
    gload16(Kp + (size_t)(kt * 64 + r) * 64 + cb / 2, Ksm + chunk * 1024);
  }
}
__device__ __forceinline__ void stage_v(const u16* Vp, int kt, int Sk, unsigned char* Vsm, int w, int l) {
#pragma unroll
  for (int j = 0; j < 2; ++j) {
    int chunk = j * 4 + w;
    int r = chunk * 8 + (l >> 3);
    int cb = ((l & 7) * 16) ^ ((r & 7) << 4);
    gload16(Vp + (size_t)r * Sk + kt * 64 + cb / 2, Vsm + chunk * 1024);
  }
}
__device__ __forceinline__ void qk_mfma(const short8 qf[2], const unsigned char* Ksm, int l, f32x4 sfr[4]) {
#pragma unroll
  for (int kc = 0; kc < 2; ++kc)
#pragma unroll
    for (int sub = 0; sub < 4; ++sub) {
      int row = sub * 16 + (l & 15);
      short8 kf = *(const short8*)(Ksm + SWZ(row, (kc * 32 + (l >> 4) * 8) * 2));
      sfr[sub] = __builtin_amdgcn_mfma_f32_16x16x32_bf16(qf[kc], kf, sfr[sub], 0, 0, 0);
    }
}
__device__ __forceinline__ void red16(float v[4]) {
#pragma unroll
  for (int d = 1; d < 16; d <<= 1)
#pragma unroll
    for (int i = 0; i < 4; ++i) v[i] += __shfl_xor(v[i], d);
}
// single pass, unnormalized: og += exp(S*scale)@V, ll += per-lane partial row sums
__device__ __forceinline__ void attn_unnorm_pass(
    const u16* Kp, const u16* Vp, int Sk, const short8 qf[2],
    unsigned char* Ksm, unsigned char* Vsm, unsigned char* Psm,
    int w, int l, f32x4 og[4], float ll[4])
{
  const int nkt = Sk >> 6;
  for (int kt = 0; kt < nkt; ++kt) {
    stage_k(Kp, kt, Ksm, w, l);
    stage_v(Vp, kt, Sk, Vsm, w, l);
    __syncthreads();
    f32x4 sfr[4] = {};
    qk_mfma(qf, Ksm, l, sfr);
#pragma unroll
    for (int sub = 0; sub < 4; ++sub)
#pragma unroll
      for (int i = 0; i < 4; ++i) {
        float p = __expf(sfr[sub][i] * 0.125f);
        ll[i] += p;
        *(u16*)(Psm + SWZ((l >> 4) * 4 + i, (sub * 16 + (l & 15)) * 2)) = f2b(p);
      }
    short8 pa[2];
    pa[0] = *(const short8*)(Psm + SWZ(l & 15, ((l >> 4) * 8) * 2));
    pa[1] = *(const short8*)(Psm + SWZ(l & 15, (32 + (l >> 4) * 8) * 2));
#pragma unroll
    for (int kc = 0; kc < 2; ++kc)
#pragma unroll
      for (int ds = 0; ds < 4; ++ds) {
        int row = ds * 16 + (l & 15);
        short8 vb = *(const short8*)(Vsm + SWZ(row, (kc * 32 + (l >> 4) * 8) * 2));
        og[ds] = __builtin_amdgcn_mfma_f32_16x16x32_bf16(pa[kc], vb, og[ds], 0, 0, 0);
      }
    __syncthreads();
  }
}

// grid (Sq/64, 12, B). Writes CTX = 0.5*(softmax(QKa)Va + softmax(QKb)Vb), merged layout.
// PROBS != null: write normalized probs for source A (f32).
__global__ __launch_bounds__(256) void attn2_kernel(
    const u16* __restrict__ Q,
    const u16* __restrict__ KA, const u16* __restrict__ VA, int SkA,
    const u16* __restrict__ KB, const u16* __restrict__ VB, int SkB,
    u16* __restrict__ CTX, float* __restrict__ PROBS, int Sq)
{
  const int h = blockIdx.y, b = blockIdx.z;
  const int q0 = blockIdx.x * 64;
  const int t = threadIdx.x, w = t >> 6, l = t & 63;
  const size_t bh = (size_t)b * 12 + h;
  const u16* Qp = Q + bh * (size_t)Sq * 64;
  const u16* KpA = KA + bh * (size_t)SkA * 64;
  const u16* VpA = VA + bh * (size_t)64 * SkA;
  const u16* KpB = KB + bh * (size_t)SkB * 64;
  const u16* VpB = VB + bh * (size_t)64 * SkB;
  __shared__ unsigned char smem[41984];
  unsigned char* Ksm = smem;
  unsigned char* Vsm = smem + 8192;
  unsigned char* Psm = smem + 16384 + w * 2048;
  unsigned char* Pf  = smem + 24576 + w * 4352;

  short8 qf[2];
  {
    int row = q0 + w * 16 + (l & 15);
    qf[0] = *(const short8*)(Qp + (size_t)row * 64 + (l >> 4) * 8);
    qf[1] = *(const short8*)(Qp + (size_t)row * 64 + 32 + (l >> 4) * 8);
  }

  f32x4 of[4] = {};
  if (PROBS) {
    // ---- source A, pass 1: denominators only (no max: scores are O(1)) ----
    float ll[4] = {0.f, 0.f, 0.f, 0.f};
    const int nkt = SkA >> 6;
    for (int kt = 0; kt < nkt; ++kt) {
      stage_k(KpA, kt, Ksm, w, l);
      __syncthreads();
      f32x4 sfr[4] = {};
      qk_mfma(qf, Ksm, l, sfr);
#pragma unroll
      for (int sub = 0; sub < 4; ++sub)
#pragma unroll
        for (int i = 0; i < 4; ++i) ll[i] += __expf(sfr[sub][i] * 0.125f);
      __syncthreads();
    }
    red16(ll);
    float rl[4];
#pragma unroll
    for (int i = 0; i < 4; ++i) rl[i] = 1.0f / ll[i];
    // ---- source A, pass 2: normalized probs out + PV ----
    const size_t pbase = (bh * Sq + q0 + w * 16);
    for (int kt = 0; kt < nkt; ++kt) {
      stage_k(KpA, kt, Ksm, w, l);
      stage_v(VpA, kt, SkA, Vsm, w, l);
      __syncthreads();
      f32x4 sfr[4] = {};
      qk_mfma(qf, Ksm, l, sfr);
#pragma unroll
      for (int sub = 0; sub < 4; ++sub)
#pragma unroll
        for (int i = 0; i < 4; ++i) {
          float p = __expf(sfr[sub][i] * 0.125f) * rl[i];
          int prow = (l >> 4) * 4 + i, pcol = sub * 16 + (l & 15);
          *(float*)(Pf + prow * 272 + pcol * 4) = p;
          *(u16*)(Psm + SWZ(prow, pcol * 2)) = f2b(p);
        }
#pragma unroll
      for (int ps = 0; ps < 4; ++ps) {   // coalesced f32x4 probs rows
        int row = ps * 4 + (l >> 4);
        f32x4 v = *(const f32x4*)(Pf + row * 272 + (l & 15) * 16);
        *(f32x4*)(PROBS + (pbase + row) * (size_t)SkA + kt * 64 + (l & 15) * 4) = v;
      }
      short8 pa[2];
      pa[0] = *(const short8*)(Psm + SWZ(l & 15, ((l >> 4) * 8) * 2));
      pa[1] = *(const short8*)(Psm + SWZ(l & 15, (32 + (l >> 4) * 8) * 2));
#pragma unroll
      for (int kc = 0; kc < 2; ++kc)
#pragma unroll
        for (int ds = 0; ds < 4; ++ds) {
          int row = ds * 16 + (l & 15);
          short8 vb = *(const short8*)(Vsm + SWZ(row, (kc * 32 + (l >> 4) * 8) * 2));
          of[ds] = __builtin_amdgcn_mfma_f32_16x16x32_bf16(pa[kc], vb, of[ds], 0, 0, 0);
        }
      __syncthreads();
    }
#pragma unroll
    for (int ds = 0; ds < 4; ++ds) of[ds] *= 0.5f;
  } else {
    float ll[4] = {0.f, 0.f, 0.f, 0.f};
    attn_unnorm_pass(KpA, VpA, SkA, qf, Ksm, Vsm, Psm, w, l, of, ll);
    red16(ll);
#pragma unroll
    for (int ds = 0; ds < 4; ++ds)
#pragma unroll
      for (int i = 0; i < 4; ++i) of[ds][i] *= 0.5f / ll[i];
  }
  // ---- source B: single unnormalized pass ----
  {
    f32x4 og[4] = {};
    float l2[4] = {0.f, 0.f, 0.f, 0.f};
    attn_unnorm_pass(KpB, VpB, SkB, qf, Ksm, Vsm, Psm, w, l, og, l2);
    red16(l2);
#pragma unroll
    for (int ds = 0; ds < 4; ++ds)
#pragma unroll
      for (int i = 0; i < 4; ++i) of[ds][i] += og[ds][i] * (0.5f / l2[i]);
  }
  // ---- write merged ctx [b][s][768] bf16 via per-wave LDS bounce ----
#pragma unroll
  for (int ds = 0; ds < 4; ++ds)
#pragma unroll
    for (int i = 0; i < 4; ++i) {
      int prow = (l >> 4) * 4 + i, pcol = ds * 16 + (l & 15);
      *(u16*)(Psm + SWZ(prow, pcol * 2)) = f2b(of[ds][i]);
    }
#pragma unroll
  for (int i = 0; i < 2; ++i) {
    int idx = i * 64 + l;
    int r = idx >> 3, off = (idx & 7) * 16;
    short8 v = *(const short8*)(Psm + SWZ(r, off));
    int s = q0 + w * 16 + r;
    *(short8*)(CTX + ((size_t)b * Sq + s) * 768 + h * 64 + off / 2) = v;
  }
}

// ---------------- output projection: CTX bf16 @ Wo^T + bo -> f32 ----------------
__global__ __launch_bounds__(256) void outproj_kernel(
    const u16* __restrict__ C, const u16* __restrict__ Wt,
    const float* __restrict__ bias, float* __restrict__ OUT)
{
  const int m0 = blockIdx.x * 128, n0 = blockIdx.y * 128;
  __shared__ unsigned char sm[32768];
  unsigned char* Asm = sm;
  unsigned char* Bsm = sm + 16384;
  const int t = threadIdx.x, w = t >> 6, l = t & 63;
  const int wm = (w & 1) * 64, wn = (w >> 1) * 64;
  f32x4 acc[4][4] = {};
  for (int k0 = 0; k0 < 768; k0 += 64) {
#pragma unroll
    for (int j = 0; j < 4; ++j) {
      int chunk = j * 4 + w;
      int r = chunk * 8 + (l >> 3);
      int cb = ((l & 7) * 16) ^ ((r & 7) << 4);
      gload16(C + (size_t)(m0 + r) * 768 + k0 + cb / 2, Asm + chunk * 1024);
    }
#pragma unroll
    for (int j = 0; j < 4; ++j) {
      int chunk = j * 4 + w;
      int r = chunk * 8 + (l >> 3);
      int cb = ((l & 7) * 16) ^ ((r & 7) << 4);
      gload16(Wt + (size_t)(n0 + r) * 768 + k0 + cb / 2, Bsm + chunk * 1024);
    }
    __syncthreads();
#pragma unroll
    for (int kc = 0; kc < 2; ++kc) {
      short8 af[4], bfr[4];
      const int koff = (kc * 32 + (l >> 4) * 8) * 2;
#pragma unroll
      for (int ms = 0; ms < 4; ++ms) {
        int row = wm + ms * 16 + (l & 15);
        af[ms] = *(const short8*)(Asm + SWZ(row, koff));
      }
#pragma unroll
      for (int ns = 0; ns < 4; ++ns) {
        int row = wn + ns * 16 + (l & 15);
        bfr[ns] = *(const short8*)(Bsm + SWZ(row, koff));
      }
#pragma unroll
      for (int ms = 0; ms < 4; ++ms)
#pragma unroll
        for (int ns = 0; ns < 4; ++ns)
          acc[ms][ns] = __builtin_amdgcn_mfma_f32_16x16x32_bf16(af[ms], bfr[ns], acc[ms][ns], 0, 0, 0);
    }
    __syncthreads();
  }
#pragma unroll
  for (int ms = 0; ms < 4; ++ms)
#pragma unroll
    for (int ns = 0; ns < 4; ++ns) {
      float bv = bias[n0 + wn + ns * 16 + (l & 15)];
#pragma unroll
      for (int i = 0; i < 4; ++i) {
        int mm = m0 + wm + ms * 16 + (l >> 4) * 4 + i;
        int nn = n0 + wn + ns * 16 + (l & 15);
        OUT[(size_t)mm * 768 + nn] = acc[ms][ns][i] + bv;
      }
    }
}

extern "C" void kernel_launch(void* const* d_in, const int* in_sizes, int n_in,
                              void* d_out, int out_size, void* d_ws, size_t ws_size,
                              hipStream_t stream)
{
  const float* hidden = (const float*)d_in[0];
  const float* text   = (const float*)d_in[1];
  const float* Wq  = (const float*)d_in[2];  const float* bq  = (const float*)d_in[3];
  const float* Wk  = (const float*)d_in[4];  const float* bk  = (const float*)d_in[5];
  const float* Wv  = (const float*)d_in[6];  const float* bv  = (const float*)d_in[7];
  const float* Wqt = (const float*)d_in[8];  const float* bqt = (const float*)d_in[9];
  const float* Wkt = (const float*)d_in[10]; const float* bkt = (const float*)d_in[11];
  const float* Wvt = (const float*)d_in[12]; const float* bvt = (const float*)d_in[13];
  const float* Wo  = (const float*)d_in[14]; const float* bo  = (const float*)d_in[15];

  u16* wt   = (u16*)d_ws;                 // 7 * 589824
  u16* xb   = wt + 7 * 589824;            // hidden bf16 (6291456) + text bf16 (3145728)
  u16* qi   = xb + 9437184;               // [8][12][1024][64]
  u16* ki   = qi + 6291456;
  u16* vti  = ki + 6291456;               // [8][12][64][1024]
  u16* qt   = vti + 6291456;              // [8][12][512][64]
  u16* ktx  = qt + 3145728;
  u16* vtt  = ktx + 3145728;              // [8][12][64][512]
  u16* cimg = vtt + 3145728;              // [8][1024][768] = 0.5*(ctx_ii+ctx_it)
  u16* ctxt = cimg + 6291456;             // [8][512][768]  = 0.5*(ctx_tt+ctx_ti)

  float* out_img  = (float*)d_out;
  float* out_text = out_img + 6291456;
  float* weights  = out_text + 3145728;

  wtrans_kernel<<<dim3(12, 12, 7), 256, 0, stream>>>(Wq, Wk, Wv, Wqt, Wkt, Wvt, Wo, wt);
  xconv_kernel<<<4608, 256, 0, stream>>>(hidden, text, xb);

  u16* wto = wt + 6 * 589824;
  proj_kernel<<<dim3(64, 18), 256, 0, stream>>>(xb, wt, bq, bk, bv, qi, ki, vti, 1024, 10);
  proj_kernel<<<dim3(32, 18), 256, 0, stream>>>(xb + 6291456, wt + 3 * 589824,
                                                bqt, bkt, bvt, qt, ktx, vtt, 512, 9);

  attn2_kernel<<<dim3(16, 12, 8), 256, 0, stream>>>(qi, ki, vti, 1024, ktx, vtt, 512,
                                                    cimg, weights, 1024);
  attn2_kernel<<<dim3(8, 12, 8), 256, 0, stream>>>(qt, ktx, vtt, 512, ki, vti, 1024,
                                                   ctxt, nullptr, 512);

  outproj_kernel<<<dim3(64, 6), 256, 0, stream>>>(cimg, wto, bo, out_img);
  outproj_kernel<<<dim3(32, 6), 256, 0, stream>>>(ctxt, wto, bo, out_text);
}

// Round 3
// 319.717 us; speedup vs baseline: 1.7728x; 1.1367x over previous
//
#include <hip/hip_runtime.h>

typedef __attribute__((ext_vector_type(4))) float f32x4;
typedef __attribute__((ext_vector_type(8))) short short8;
typedef __attribute__((ext_vector_type(4))) unsigned short us4;
typedef unsigned short u16;
typedef unsigned char uchar;

__device__ __forceinline__ u16 f2b(float f) {
  union { float f; unsigned u; } a; a.f = f;
  unsigned r = a.u + 0x7fffu + ((a.u >> 16) & 1u);
  return (u16)(r >> 16);
}
// XOR swizzle for [rows][128B] LDS tiles
#define SWZ(r, byteoff) ((((r) * 128) + (byteoff)) ^ (((r) & 7) << 4))

typedef __attribute__((address_space(1))) const void* gp1;
typedef __attribute__((address_space(3))) void* lp3;
__device__ __forceinline__ void gload16(const void* g, void* lds_wave_uniform_base) {
  __builtin_amdgcn_global_load_lds((gp1)g, (lp3)lds_wave_uniform_base, 16, 0, 0);
}

// ============ prep: weight transpose+bf16 (wgs 0..1007) | X f32->bf16 (rest) ============
__global__ __launch_bounds__(256) void prep_kernel(
    const float* w0, const float* w1, const float* w2, const float* w3,
    const float* w4, const float* w5, const float* w6, u16* wt,
    const float* __restrict__ h, const float* __restrict__ tx, u16* __restrict__ xb)
{
  const int bid = blockIdx.x, t = threadIdx.x;
  if (bid < 1008) {
    __shared__ float tile[64][65];
    const float* Ws[7] = {w0, w1, w2, w3, w4, w5, w6};
    int z = bid / 144, rem = bid % 144;
    const float* W = Ws[z];
    u16* out = wt + (size_t)z * 589824;
    const int r0 = (rem / 12) * 64, c0 = (rem % 12) * 64;
#pragma unroll
    for (int i = 0; i < 4; ++i) {
      int idx = i * 256 + t;
      int r = idx >> 4, c = (idx & 15) * 4;
      f32x4 v = *(const f32x4*)(W + (size_t)(r0 + r) * 768 + (c0 + c));
      tile[r][c + 0] = v[0]; tile[r][c + 1] = v[1];
      tile[r][c + 2] = v[2]; tile[r][c + 3] = v[3];
    }
    __syncthreads();
#pragma unroll
    for (int i = 0; i < 4; ++i) {
      int idx = i * 256 + t;
      int rn = idx >> 4, c = (idx & 15) * 4;
      us4 o;
      o[0] = f2b(tile[c + 0][rn]); o[1] = f2b(tile[c + 1][rn]);
      o[2] = f2b(tile[c + 2][rn]); o[3] = f2b(tile[c + 3][rn]);
      *(us4*)(out + (size_t)(c0 + rn) * 768 + (r0 + c)) = o;
    }
  } else {
    size_t e = ((size_t)(bid - 1008) * 256 + t) * 8;
    const float* src; size_t off;
    if (e < 6291456) { src = h; off = e; } else { src = tx; off = e - 6291456; }
    f32x4 v0 = *(const f32x4*)(src + off), v1 = *(const f32x4*)(src + off + 4);
    short8 r;
    r[0] = (short)f2b(v0[0]); r[1] = (short)f2b(v0[1]); r[2] = (short)f2b(v0[2]); r[3] = (short)f2b(v0[3]);
    r[4] = (short)f2b(v1[0]); r[5] = (short)f2b(v1[1]); r[6] = (short)f2b(v1[2]); r[7] = (short)f2b(v1[3]);
    *(short8*)(xb + e) = r;
  }
}

// ============ merged QKV projection (img ids 0..1151, text 1152..1727) ============
__global__ __launch_bounds__(256) void proj_kernel(
    const u16* __restrict__ Xb, const u16* __restrict__ wt,
    const float* __restrict__ bq, const float* __restrict__ bk, const float* __restrict__ bv,
    const float* __restrict__ bqt, const float* __restrict__ bkt, const float* __restrict__ bvt,
    u16* __restrict__ qi, u16* __restrict__ ki, u16* __restrict__ vti,
    u16* __restrict__ qt, u16* __restrict__ ktx, u16* __restrict__ vtt)
{
  const int bid = blockIdx.x;
  const int wk = (bid & 7) * 216 + (bid >> 3);     // bijective, 1728%8==0
  const bool img = wk < 1152;
  const int id = img ? wk : wk - 1152;
  const int y = img ? (id >> 6) : (id >> 5);       // 0..17: same-y blocks share weights
  const int x = img ? (id & 63) : (id & 31);
  const int z = y / 6, n0 = (y % 6) * 128, m0 = x * 128;
  const int S = img ? 1024 : 512, logS = img ? 10 : 9;
  const u16* X = img ? Xb : Xb + 6291456;
  const u16* Wt = wt + (img ? 0 : (size_t)3 * 589824) + (size_t)y * 98304;
  const float* bias = img ? (z == 0 ? bq : z == 1 ? bk : bv)
                          : (z == 0 ? bqt : z == 1 ? bkt : bvt);
  u16* out = img ? (z == 0 ? qi : z == 1 ? ki : vti)
                 : (z == 0 ? qt : z == 1 ? ktx : vtt);
  const bool vmode = (z == 2);
  __shared__ unsigned char sm[36864];
  unsigned char* Asm = sm;
  unsigned char* Bsm = sm + 16384;
  const int t = threadIdx.x, w = t >> 6, l = t & 63;
  const int wm = (w & 1) * 64, wn = (w >> 1) * 64;
  f32x4 acc[4][4] = {};
  for (int k0 = 0; k0 < 768; k0 += 64) {
#pragma unroll
    for (int j = 0; j < 4; ++j) {
      int chunk = j * 4 + w;
      int r = chunk * 8 + (l >> 3);
      int cb = ((l & 7) * 16) ^ ((r & 7) << 4);
      gload16(X + (size_t)(m0 + r) * 768 + k0 + cb / 2, Asm + chunk * 1024);
    }
#pragma unroll
    for (int j = 0; j < 4; ++j) {
      int chunk = j * 4 + w;
      int r = chunk * 8 + (l >> 3);
      int cb = ((l & 7) * 16) ^ ((r & 7) << 4);
      gload16(Wt + (size_t)r * 768 + k0 + cb / 2, Bsm + chunk * 1024);
    }
    __syncthreads();
#pragma unroll
    for (int kc = 0; kc < 2; ++kc) {
      short8 af[4], bfr[4];
      const int koff = (kc * 32 + (l >> 4) * 8) * 2;
#pragma unroll
      for (int ms = 0; ms < 4; ++ms) {
        int row = wm + ms * 16 + (l & 15);
        af[ms] = *(const short8*)(Asm + SWZ(row, koff));
      }
#pragma unroll
      for (int ns = 0; ns < 4; ++ns) {
        int row = wn + ns * 16 + (l & 15);
        bfr[ns] = *(const short8*)(Bsm + SWZ(row, koff));
      }
      __builtin_amdgcn_s_setprio(1);
#pragma unroll
      for (int ms = 0; ms < 4; ++ms)
#pragma unroll
        for (int ns = 0; ns < 4; ++ns)
          acc[ms][ns] = __builtin_amdgcn_mfma_f32_16x16x32_bf16(af[ms], bfr[ns], acc[ms][ns], 0, 0, 0);
      __builtin_amdgcn_s_setprio(0);
    }
    __syncthreads();
  }
  float bvv[4];
#pragma unroll
  for (int ns = 0; ns < 4; ++ns) bvv[ns] = bias[n0 + wn + ns * 16 + (l & 15)];
#pragma unroll
  for (int ms = 0; ms < 4; ++ms)
#pragma unroll
    for (int ns = 0; ns < 4; ++ns)
#pragma unroll
      for (int i = 0; i < 4; ++i) {
        u16 u = f2b(acc[ms][ns][i] + bvv[ns]);
        int mm = wm + ms * 16 + (l >> 4) * 4 + i;
        int nn = wn + ns * 16 + (l & 15);
        int row = vmode ? nn : mm, col = vmode ? mm : nn;
        *(u16*)(sm + row * 272 + col * 2) = u;
      }
  __syncthreads();
  if (!vmode) {
#pragma unroll
    for (int i = 0; i < 8; ++i) {
      int idx = i * 256 + t;
      int r = idx >> 4, c = (idx & 15) * 8;
      short8 v = *(const short8*)(sm + r * 272 + c * 2);
      int sg = m0 + r, b = sg >> logS, s = sg & (S - 1);
      int n = n0 + c, hh = n >> 6, d = n & 63;
      *(short8*)(out + (((size_t)b * 12 + hh) * S + s) * 64 + d) = v;
    }
  } else {
#pragma unroll
    for (int i = 0; i < 8; ++i) {
      int idx = i * 256 + t;
      int r = idx >> 4, c = (idx & 15) * 8;
      short8 v = *(const short8*)(sm + r * 272 + c * 2);
      int n = n0 + r, hh = n >> 6, d = n & 63;
      int sg = m0 + c, b = sg >> logS, s = sg & (S - 1);
      *(short8*)(out + (((size_t)b * 12 + hh) * 64 + d) * S + s) = v;
    }
  }
}

// ============ attention helpers ============
__device__ __forceinline__ void stage_k(const u16* Kp, int kt, uchar* Ksm, int w, int l) {
#pragma unroll
  for (int j = 0; j < 2; ++j) {
    int chunk = j * 4 + w;
    int r = chunk * 8 + (l >> 3);
    int cb = ((l & 7) * 16) ^ ((r & 7) << 4);
    gload16(Kp + (size_t)(kt * 64 + r) * 64 + cb / 2, Ksm + chunk * 1024);
  }
}
__device__ __forceinline__ void stage_v(const u16* Vp, int kt, int Sk, uchar* Vsm, int w, int l) {
#pragma unroll
  for (int j = 0; j < 2; ++j) {
    int chunk = j * 4 + w;
    int r = chunk * 8 + (l >> 3);
    int cb = ((l & 7) * 16) ^ ((r & 7) << 4);
    gload16(Vp + (size_t)r * Sk + kt * 64 + cb / 2, Vsm + chunk * 1024);
  }
}
__device__ __forceinline__ void qk8(const short8 qf[2], const uchar* Ksm, int l, f32x4 sfr[4]) {
  __builtin_amdgcn_s_setprio(1);
#pragma unroll
  for (int kc = 0; kc < 2; ++kc)
#pragma unroll
    for (int sub = 0; sub < 4; ++sub) {
      int row = sub * 16 + (l & 15);
      short8 kf = *(const short8*)(Ksm + SWZ(row, (kc * 32 + (l >> 4) * 8) * 2));
      sfr[sub] = __builtin_amdgcn_mfma_f32_16x16x32_bf16(qf[kc], kf, sfr[sub], 0, 0, 0);
    }
  __builtin_amdgcn_s_setprio(0);
}
// PV: A-fragments from Pf (f32 P tile, per-wave, stride 272B), B from swizzled Vsm
__device__ __forceinline__ void pv8(const uchar* Pf, const uchar* Vsm, int l, f32x4 og[4]) {
  const uchar* base = Pf + (l & 15) * 272 + (l >> 4) * 32;
  f32x4 a0 = *(const f32x4*)(base);
  f32x4 a1 = *(const f32x4*)(base + 16);
  f32x4 b0 = *(const f32x4*)(base + 128);
  f32x4 b1 = *(const f32x4*)(base + 144);
  short8 pa0, pa1;
  pa0[0] = (short)f2b(a0[0]); pa0[1] = (short)f2b(a0[1]); pa0[2] = (short)f2b(a0[2]); pa0[3] = (short)f2b(a0[3]);
  pa0[4] = (short)f2b(a1[0]); pa0[5] = (short)f2b(a1[1]); pa0[6] = (short)f2b(a1[2]); pa0[7] = (short)f2b(a1[3]);
  pa1[0] = (short)f2b(b0[0]); pa1[1] = (short)f2b(b0[1]); pa1[2] = (short)f2b(b0[2]); pa1[3] = (short)f2b(b0[3]);
  pa1[4] = (short)f2b(b1[0]); pa1[5] = (short)f2b(b1[1]); pa1[6] = (short)f2b(b1[2]); pa1[7] = (short)f2b(b1[3]);
  __builtin_amdgcn_s_setprio(1);
#pragma unroll
  for (int ds = 0; ds < 4; ++ds) {
    int row = ds * 16 + (l & 15);
    short8 vb0 = *(const short8*)(Vsm + SWZ(row, ((l >> 4) * 8) * 2));
    short8 vb1 = *(const short8*)(Vsm + SWZ(row, (32 + (l >> 4) * 8) * 2));
    og[ds] = __builtin_amdgcn_mfma_f32_16x16x32_bf16(pa0, vb0, og[ds], 0, 0, 0);
    og[ds] = __builtin_amdgcn_mfma_f32_16x16x32_bf16(pa1, vb1, og[ds], 0, 0, 0);
  }
  __builtin_amdgcn_s_setprio(0);
}
__device__ __forceinline__ void red16(float v[4]) {
#pragma unroll
  for (int d = 1; d < 16; d <<= 1)
#pragma unroll
    for (int i = 0; i < 4; ++i) v[i] += __shfl_xor(v[i], d);
}
// single pass, double-buffered, unnormalized: og += exp(S/8)@V; ll += partial row sums
__device__ __forceinline__ void pass_unnorm(
    const u16* Kp, const u16* Vp, int Sk, const short8 qf[2],
    uchar* Ks0, uchar* Ks1, uchar* Vs0, uchar* Vs1, uchar* Pf,
    int w, int l, f32x4 og[4], float ll[4])
{
  const int nkt = Sk >> 6;
  stage_k(Kp, 0, Ks0, w, l);
  stage_v(Vp, 0, Sk, Vs0, w, l);
  __syncthreads();
  for (int kt = 0; kt < nkt; ++kt) {
    uchar* Kc = (kt & 1) ? Ks1 : Ks0;
    uchar* Vc = (kt & 1) ? Vs1 : Vs0;
    if (kt + 1 < nkt) {
      stage_k(Kp, kt + 1, (kt & 1) ? Ks0 : Ks1, w, l);
      stage_v(Vp, kt + 1, Sk, (kt & 1) ? Vs0 : Vs1, w, l);
    }
    f32x4 sfr[4] = {};
    qk8(qf, Kc, l, sfr);
#pragma unroll
    for (int sub = 0; sub < 4; ++sub)
#pragma unroll
      for (int i = 0; i < 4; ++i) {
        float p = __expf(sfr[sub][i] * 0.125f);
        ll[i] += p;
        *(float*)(Pf + ((l >> 4) * 4 + i) * 272 + (sub * 16 + (l & 15)) * 4) = p;
      }
    pv8(Pf, Vc, l, og);
    __syncthreads();
  }
}

// ============ merged dual-source attention (img ids 0..1535, text 1536..2303) ============
__global__ __launch_bounds__(256) void attn_kernel(
    const u16* __restrict__ qi, const u16* __restrict__ ki, const u16* __restrict__ vti,
    const u16* __restrict__ qt, const u16* __restrict__ ktx, const u16* __restrict__ vtt,
    u16* __restrict__ cimg, u16* __restrict__ ctxt, float* __restrict__ weights)
{
  __shared__ uchar smem[50176];
  const int t = threadIdx.x, w = t >> 6, l = t & 63;
  uchar* Ks0 = smem;
  uchar* Ks1 = smem + 8192;
  uchar* Vs0 = smem + 16384;
  uchar* Vs1 = smem + 24576;
  uchar* Pf  = smem + 32768 + w * 4352;

  const int bid = blockIdx.x;
  const int wk = (bid & 7) * 288 + (bid >> 3);     // bijective, 2304%8==0
  const bool img = wk < 1536;
  const int id = img ? wk : wk - 1536;
  const int x = img ? (id & 15) : (id & 7);
  const int head = img ? (id >> 4) : (id >> 3);    // b*12+h: same-head wgs contiguous -> same XCD
  const int b = head / 12, h = head % 12;
  const int Sq = img ? 1024 : 512;
  const int SkA = img ? 1024 : 512, SkB = img ? 512 : 1024;
  const u16* Qp = (img ? qi : qt) + (size_t)head * Sq * 64;
  const u16* KpA = (img ? ki : ktx) + (size_t)head * SkA * 64;
  const u16* VpA = (img ? vti : vtt) + (size_t)head * 64 * SkA;
  const u16* KpB = (img ? ktx : ki) + (size_t)head * SkB * 64;
  const u16* VpB = (img ? vtt : vti) + (size_t)head * 64 * SkB;
  u16* CTX = img ? cimg : ctxt;
  float* PROBS = img ? weights : nullptr;
  const int q0 = x * 64;

  short8 qf[2];
  {
    int row = q0 + w * 16 + (l & 15);
    qf[0] = *(const short8*)(Qp + (size_t)row * 64 + (l >> 4) * 8);
    qf[1] = *(const short8*)(Qp + (size_t)row * 64 + 32 + (l >> 4) * 8);
  }

  f32x4 of[4] = {};
  if (PROBS) {
    // ---- pass 1 over A: denominators only (K dbuf) ----
    float ll[4] = {0.f, 0.f, 0.f, 0.f};
    const int nkt = SkA >> 6;
    stage_k(KpA, 0, Ks0, w, l);
    __syncthreads();
    for (int kt = 0; kt < nkt; ++kt) {
      uchar* Kc = (kt & 1) ? Ks1 : Ks0;
      if (kt + 1 < nkt) stage_k(KpA, kt + 1, (kt & 1) ? Ks0 : Ks1, w, l);
      f32x4 sfr[4] = {};
      qk8(qf, Kc, l, sfr);
#pragma unroll
      for (int sub = 0; sub < 4; ++sub)
#pragma unroll
        for (int i = 0; i < 4; ++i) ll[i] += __expf(sfr[sub][i] * 0.125f);
      __syncthreads();
    }
    // pass-2 prologue staged early; reduction VALU hides part of the latency
    stage_k(KpA, 0, Ks0, w, l);
    stage_v(VpA, 0, SkA, Vs0, w, l);
    red16(ll);
    float rl[4];
#pragma unroll
    for (int i = 0; i < 4; ++i) rl[i] = 1.0f / ll[i];
    __syncthreads();
    // ---- pass 2 over A: normalized probs out + PV (K,V dbuf) ----
    const size_t pbase = ((size_t)head * Sq + q0 + w * 16);
    for (int kt = 0; kt < nkt; ++kt) {
      uchar* Kc = (kt & 1) ? Ks1 : Ks0;
      uchar* Vc = (kt & 1) ? Vs1 : Vs0;
      if (kt + 1 < nkt) {
        stage_k(KpA, kt + 1, (kt & 1) ? Ks0 : Ks1, w, l);
        stage_v(VpA, kt + 1, SkA, (kt & 1) ? Vs0 : Vs1, w, l);
      }
      f32x4 sfr[4] = {};
      qk8(qf, Kc, l, sfr);
#pragma unroll
      for (int sub = 0; sub < 4; ++sub)
#pragma unroll
        for (int i = 0; i < 4; ++i) {
          float p = __expf(sfr[sub][i] * 0.125f) * rl[i];
          *(float*)(Pf + ((l >> 4) * 4 + i) * 272 + (sub * 16 + (l & 15)) * 4) = p;
        }
#pragma unroll
      for (int ps = 0; ps < 4; ++ps) {             // coalesced f32x4 probs rows
        int row = ps * 4 + (l >> 4);
        f32x4 v = *(const f32x4*)(Pf + row * 272 + (l & 15) * 16);
        *(f32x4*)(PROBS + (pbase + row) * (size_t)SkA + kt * 64 + (l & 15) * 4) = v;
      }
      pv8(Pf, Vc, l, of);
      __syncthreads();
    }
#pragma unroll
    for (int ds = 0; ds < 4; ++ds) of[ds] *= 0.5f;
  } else {
    float ll[4] = {0.f, 0.f, 0.f, 0.f};
    pass_unnorm(KpA, VpA, SkA, qf, Ks0, Ks1, Vs0, Vs1, Pf, w, l, of, ll);
    red16(ll);
#pragma unroll
    for (int ds = 0; ds < 4; ++ds)
#pragma unroll
      for (int i = 0; i < 4; ++i) of[ds][i] *= 0.5f / ll[i];
  }
  // ---- source B: single unnormalized dbuf pass ----
  {
    f32x4 og[4] = {};
    float l2[4] = {0.f, 0.f, 0.f, 0.f};
    pass_unnorm(KpB, VpB, SkB, qf, Ks0, Ks1, Vs0, Vs1, Pf, w, l, og, l2);
    red16(l2);
#pragma unroll
    for (int ds = 0; ds < 4; ++ds)
#pragma unroll
      for (int i = 0; i < 4; ++i) of[ds][i] += og[ds][i] * (0.5f / l2[i]);
  }
  // ---- write merged ctx [b][s][768] bf16 via per-wave Pf bounce ----
#pragma unroll
  for (int ds = 0; ds < 4; ++ds)
#pragma unroll
    for (int i = 0; i < 4; ++i)
      *(float*)(Pf + ((l >> 4) * 4 + i) * 272 + (ds * 16 + (l & 15)) * 4) = of[ds][i];
#pragma unroll
  for (int i = 0; i < 2; ++i) {
    int it = i * 64 + l;
    int r = it >> 3, cg = it & 7;
    f32x4 v0 = *(const f32x4*)(Pf + r * 272 + cg * 32);
    f32x4 v1 = *(const f32x4*)(Pf + r * 272 + cg * 32 + 16);
    short8 o;
    o[0] = (short)f2b(v0[0]); o[1] = (short)f2b(v0[1]); o[2] = (short)f2b(v0[2]); o[3] = (short)f2b(v0[3]);
    o[4] = (short)f2b(v1[0]); o[5] = (short)f2b(v1[1]); o[6] = (short)f2b(v1[2]); o[7] = (short)f2b(v1[3]);
    int s = q0 + w * 16 + r;
    *(short8*)(CTX + ((size_t)b * Sq + s) * 768 + h * 64 + cg * 8) = o;
  }
}

// ============ merged output projection (img ids 0..383, text 384..575) ============
__global__ __launch_bounds__(256) void outproj_kernel(
    const u16* __restrict__ cimg, const u16* __restrict__ ctxt,
    const u16* __restrict__ Wto, const float* __restrict__ bias,
    float* __restrict__ out_img, float* __restrict__ out_text)
{
  const int bid = blockIdx.x;
  const int wk = (bid & 7) * 72 + (bid >> 3);      // bijective, 576%8==0
  const bool img = wk < 384;
  const int id = img ? wk : wk - 384;
  const int y = img ? (id >> 6) : (id >> 5);       // same-y blocks share Wo panel
  const int x = img ? (id & 63) : (id & 31);
  const u16* C = img ? cimg : ctxt;
  float* OUT = img ? out_img : out_text;
  const int m0 = x * 128, n0 = y * 128;
  __shared__ unsigned char sm[32768];
  unsigned char* Asm = sm;
  unsigned char* Bsm = sm + 16384;
  const int t = threadIdx.x, w = t >> 6, l = t & 63;
  const int wm = (w & 1) * 64, wn = (w >> 1) * 64;
  f32x4 acc[4][4] = {};
  for (int k0 = 0; k0 < 768; k0 += 64) {
#pragma unroll
    for (int j = 0; j < 4; ++j) {
      int chunk = j * 4 + w;
      int r = chunk * 8 + (l >> 3);
      int cb = ((l & 7) * 16) ^ ((r & 7) << 4);
      gload16(C + (size_t)(m0 + r) * 768 + k0 + cb / 2, Asm + chunk * 1024);
    }
#pragma unroll
    for (int j = 0; j < 4; ++j) {
      int chunk = j * 4 + w;
      int r = chunk * 8 + (l >> 3);
      int cb = ((l & 7) * 16) ^ ((r & 7) << 4);
      gload16(Wto + (size_t)(n0 + r) * 768 + k0 + cb / 2, Bsm + chunk * 1024);
    }
    __syncthreads();
#pragma unroll
    for (int kc = 0; kc < 2; ++kc) {
      short8 af[4], bfr[4];
      const int koff = (kc * 32 + (l >> 4) * 8) * 2;
#pragma unroll
      for (int ms = 0; ms < 4; ++ms) {
        int row = wm + ms * 16 + (l & 15);
        af[ms] = *(const short8*)(Asm + SWZ(row, koff));
      }
#pragma unroll
      for (int ns = 0; ns < 4; ++ns) {
        int row = wn + ns * 16 + (l & 15);
        bfr[ns] = *(const short8*)(Bsm + SWZ(row, koff));
      }
      __builtin_amdgcn_s_setprio(1);
#pragma unroll
      for (int ms = 0; ms < 4; ++ms)
#pragma unroll
        for (int ns = 0; ns < 4; ++ns)
          acc[ms][ns] = __builtin_amdgcn_mfma_f32_16x16x32_bf16(af[ms], bfr[ns], acc[ms][ns], 0, 0, 0);
      __builtin_amdgcn_s_setprio(0);
    }
    __syncthreads();
  }
#pragma unroll
  for (int ms = 0; ms < 4; ++ms)
#pragma unroll
    for (int ns = 0; ns < 4; ++ns) {
      float bv = bias[n0 + wn + ns * 16 + (l & 15)];
#pragma unroll
      for (int i = 0; i < 4; ++i) {
        int mm = m0 + wm + ms * 16 + (l >> 4) * 4 + i;
        int nn = n0 + wn + ns * 16 + (l & 15);
        OUT[(size_t)mm * 768 + nn] = acc[ms][ns][i] + bv;
      }
    }
}

extern "C" void kernel_launch(void* const* d_in, const int* in_sizes, int n_in,
                              void* d_out, int out_size, void* d_ws, size_t ws_size,
                              hipStream_t stream)
{
  const float* hidden = (const float*)d_in[0];
  const float* text   = (const float*)d_in[1];
  const float* Wq  = (const float*)d_in[2];  const float* bq  = (const float*)d_in[3];
  const float* Wk  = (const float*)d_in[4];  const float* bk  = (const float*)d_in[5];
  const float* Wv  = (const float*)d_in[6];  const float* bv  = (const float*)d_in[7];
  const float* Wqt = (const float*)d_in[8];  const float* bqt = (const float*)d_in[9];
  const float* Wkt = (const float*)d_in[10]; const float* bkt = (const float*)d_in[11];
  const float* Wvt = (const float*)d_in[12]; const float* bvt = (const float*)d_in[13];
  const float* Wo  = (const float*)d_in[14]; const float* bo  = (const float*)d_in[15];

  u16* wt   = (u16*)d_ws;                 // 7 * 589824
  u16* xb   = wt + 7 * 589824;            // hidden bf16 (6291456) + text bf16 (3145728)
  u16* qi   = xb + 9437184;               // [8][12][1024][64]
  u16* ki   = qi + 6291456;
  u16* vti  = ki + 6291456;               // [8][12][64][1024]
  u16* qt   = vti + 6291456;              // [8][12][512][64]
  u16* ktx  = qt + 3145728;
  u16* vtt  = ktx + 3145728;              // [8][12][64][512]
  u16* cimg = vtt + 3145728;              // [8][1024][768] = 0.5*(ctx_ii+ctx_it)
  u16* ctxt = cimg + 6291456;             // [8][512][768]  = 0.5*(ctx_tt+ctx_ti)

  float* out_img  = (float*)d_out;
  float* out_text = out_img + 6291456;
  float* weights  = out_text + 3145728;

  prep_kernel<<<5616, 256, 0, stream>>>(Wq, Wk, Wv, Wqt, Wkt, Wvt, Wo, wt,
                                        hidden, text, xb);
  proj_kernel<<<1728, 256, 0, stream>>>(xb, wt, bq, bk, bv, bqt, bkt, bvt,
                                        qi, ki, vti, qt, ktx, vtt);
  attn_kernel<<<2304, 256, 0, stream>>>(qi, ki, vti, qt, ktx, vtt,
                                        cimg, ctxt, weights);
  outproj_kernel<<<576, 256, 0, stream>>>(cimg, ctxt, wt + 6 * 589824, bo,
                                          out_img, out_text);
}